// Round 6
// baseline (174.208 us; speedup 1.0000x reference)
//
#include <hip/hip_runtime.h>

// LocallyConnected2d: out[b,o,p,q] = sum_{i,kh,kw} x[b,i,2p+kh,2q+kw] * w[o,i,p,q,kh*3+kw]
// x: (8,32,64,64) f32, w: (1,32,32,31,31,9) f32, out: (8,32,31,31) f32
//
// Lanes = o (32) so x reads are wave-broadcast; block = (p, qg of 16 q, ig of 4 i),
// 512 thr = 32 o x 16 dq. Grid 31*2*8 = 496 blocks, each stages its EXCLUSIVE
// weight slice (weight read once from HBM device-wide) + a 14 KB x slice.
//  - x LDS: [b][ii][kh][36], cols 2*q0+c (c<=32, clamped) - reads broadcast across o.
//  - w LDS: [o][145] (odd stride -> o-lanes hit distinct banks), dbuf per i.
//  - i-partials combined via atomicAdd after hipMemsetAsync(out,0) (in-stream, capture-safe).

#define GLD_LDS(gp, lp)                                              \
    __builtin_amdgcn_global_load_lds(                                \
        (const __attribute__((address_space(1))) void*)(gp),         \
        (__attribute__((address_space(3))) void*)(lp), 4, 0, 0)

__global__ __launch_bounds__(512, 2) void lc2d_kernel(const float* __restrict__ x,
                                                      const float* __restrict__ wgt,
                                                      float* __restrict__ out) {
    __shared__ float xs[3584];        // 3456 used + stage-pad (7*512)
    __shared__ float ws[2][5120];     // 4640 used + stage-pad (10*512), dbuf

    const int t  = threadIdx.x;
    const int o  = t & 31;
    const int dq = t >> 5;            // 0..15
    const int bid = blockIdx.x;
    const int p  = bid >> 4;          // 0..30
    const int qg = (bid >> 3) & 1;
    const int ig = bid & 7;
    const int i0 = ig * 4;
    const int q0 = qg << 4;
    const int q  = q0 + dq;           // q=31 (qg=1,dq=15) computes dup, never stored
    const int waveBase = t & ~63;

    // ---- stage x: xs[((b*4+ii)*3+kh)*36 + c] = x[b][i0+ii][2p+kh][2*q0+min(c,xlim)]
    const int xlim = 62 - 2 * q0;     // 62 (qg0) / 30 (qg1): keep cols in-bounds
    const int xrow = 2 * p;
#pragma unroll
    for (int j = 0; j < 7; ++j) {
        int f = t + j * 512; f = (f < 3455) ? f : 3455;   // clamp GLOBAL addr only; LDS slot stays linear
        const int r  = f / 36;
        const int c  = f - r * 36;
        const int b  = r / 12;
        const int r2 = r - b * 12;
        const int ii = r2 / 3;
        const int kh = r2 - ii * 3;
        const int gc = (c < xlim) ? c : xlim;
        const float* gp = x + ((size_t)b * 131072 + (size_t)(i0 + ii) * 4096
                               + (size_t)(xrow + kh) * 64 + 2 * q0 + gc);
        GLD_LDS(gp, &xs[j * 512 + waveBase]);
    }

    // ---- i-independent w staging bases: ws[buf][o*145+off] <- wgt[(o*32+i)*8649 + p*279 + q0*9 + off]
    int bw[10];
    const int lim = (qg == 0) ? 143 : 134;   // valid words per o-seg - 1 (16 vs 15 q's)
    const int pqb = p * 279 + q0 * 9;
#pragma unroll
    for (int j = 0; j < 10; ++j) {
        int f = t + j * 512; f = (f < 4639) ? f : 4639;
        const int os  = f / 145;
        const int off = f - os * 145;
        const int go  = (off < lim) ? off : lim;          // pad words dup-load, never read
        bw[j] = os * (32 * 8649) + pqb + go;
    }

#pragma unroll
    for (int j = 0; j < 10; ++j)
        GLD_LDS(wgt + (size_t)(bw[j] + i0 * 8649), &ws[0][j * 512 + waveBase]);

    float acc[8];
#pragma unroll
    for (int b = 0; b < 8; ++b) acc[b] = 0.f;

    __syncthreads();                  // x + w[i0] staged (barrier drains vmcnt)

#pragma unroll
    for (int ii = 0; ii < 4; ++ii) {
        if (ii < 3) {                 // prefetch next i into other buffer
            const int inext = i0 + ii + 1;
#pragma unroll
            for (int j = 0; j < 10; ++j)
                GLD_LDS(wgt + (size_t)(bw[j] + inext * 8649), &ws[(ii + 1) & 1][j * 512 + waveBase]);
        }

        const float* wb = ws[ii & 1];
        float wv[9];
        const int wbase = o * 145 + dq * 9;               // stride-145 across o-lanes: bank-bijective
#pragma unroll
        for (int k = 0; k < 9; ++k) wv[k] = wb[wbase + k];

        const int xdq = 2 * dq;
#pragma unroll
        for (int kh = 0; kh < 3; ++kh) {
#pragma unroll
            for (int b = 0; b < 8; ++b) {
                const int base = ((b * 4 + ii) * 3 + kh) * 36 + xdq;   // one base reg + imm offsets
                const float2 a = *reinterpret_cast<const float2*>(&xs[base]);  // cols 2q,2q+1
                const float c1 = xs[base + 2];                                  // col 2q+2
                acc[b] += wv[kh * 3 + 0] * a.x + wv[kh * 3 + 1] * a.y + wv[kh * 3 + 2] * c1;
            }
        }
        __syncthreads();              // compute(ii) reads done before ws[ii&1] is re-staged
    }

    if (q <= 30) {
#pragma unroll
        for (int b = 0; b < 8; ++b)
            atomicAdd(&out[(((size_t)b * 32 + o) * 31 + p) * 31 + q], acc[b]);
    }
}

extern "C" void kernel_launch(void* const* d_in, const int* in_sizes, int n_in,
                              void* d_out, int out_size, void* d_ws, size_t ws_size,
                              hipStream_t stream) {
    const float* x = (const float*)d_in[0];
    const float* w = (const float*)d_in[1];
    float* out = (float*)d_out;
    hipMemsetAsync(out, 0, (size_t)out_size * sizeof(float), stream);  // atomics accumulate on zeroed out
    lc2d_kernel<<<dim3(31 * 2 * 8), dim3(512), 0, stream>>>(x, w, out);
}

// Round 7
// 128.612 us; speedup vs baseline: 1.3545x; 1.3545x over previous
//
#include <hip/hip_runtime.h>

// LocallyConnected2d: out[b,o,p,q] = sum_{i,kh,kw} x[b,i,2p+kh,2q+kw] * w[o,i,p,q,kh*3+kw]
// x: (8,32,64,64) f32, w: (1,32,32,31,31,9) f32, out: (8,32,31,31) f32
//
// Lanes = o (32) so x reads are wave-broadcast; block = (p, qg of 16 q, ig of 4 i),
// 512 thr = 32 o x 16 dq. Grid 31*2*8 = 496 blocks, each stages its EXCLUSIVE
// weight slice (weight read once from HBM device-wide) + a 14 KB x slice.
//  - x LDS: [b][ii][kh][36], cols 2*q0+c (clamped) - reads broadcast across o.
//  - w LDS: [o][145] (odd stride -> o-lanes hit distinct banks), dbuf per i.
//  - i-partials: R6's atomicAdd caused 106 MB of HBM RMW writes (device-scope
//    atomics bypass the non-coherent per-XCD L2s). Now: coalesced partial
//    stores to d_ws (store addr = base + threadIdx, contiguous) + reduce kernel.

#define NPART 246016              // 8b * 961pq * 32o floats per ig-copy
#define WS_NEED ((size_t)8 * NPART * 4)

#define GLD_LDS(gp, lp)                                              \
    __builtin_amdgcn_global_load_lds(                                \
        (const __attribute__((address_space(1))) void*)(gp),         \
        (__attribute__((address_space(3))) void*)(lp), 4, 0, 0)

template <bool USE_WS>
__global__ __launch_bounds__(512, 2) void lc2d_kernel(const float* __restrict__ x,
                                                      const float* __restrict__ wgt,
                                                      float* __restrict__ outOrPart) {
    __shared__ float xs[3584];        // 3456 used + stage-pad (7*512)
    __shared__ float ws[2][5120];     // 4640 used + stage-pad (10*512), dbuf

    const int t  = threadIdx.x;
    const int o  = t & 31;
    const int dq = t >> 5;            // 0..15
    const int bid = blockIdx.x;
    const int p  = bid >> 4;          // 0..30
    const int qg = (bid >> 3) & 1;
    const int ig = bid & 7;
    const int i0 = ig * 4;
    const int q0 = qg << 4;
    const int q  = q0 + dq;           // q=31 (qg=1,dq=15) computes dup, never stored
    const int waveBase = t & ~63;

    // ---- stage x: xs[((b*4+ii)*3+kh)*36 + c] = x[b][i0+ii][2p+kh][2*q0+min(c,xlim)]
    const int xlim = 62 - 2 * q0;     // 62 (qg0) / 30 (qg1): keep cols in-bounds
    const int xrow = 2 * p;
#pragma unroll
    for (int j = 0; j < 7; ++j) {
        int f = t + j * 512; f = (f < 3455) ? f : 3455;   // clamp GLOBAL addr only; LDS slot stays linear
        const int r  = f / 36;
        const int c  = f - r * 36;
        const int b  = r / 12;
        const int r2 = r - b * 12;
        const int ii = r2 / 3;
        const int kh = r2 - ii * 3;
        const int gc = (c < xlim) ? c : xlim;
        const float* gp = x + ((size_t)b * 131072 + (size_t)(i0 + ii) * 4096
                               + (size_t)(xrow + kh) * 64 + 2 * q0 + gc);
        GLD_LDS(gp, &xs[j * 512 + waveBase]);
    }

    // ---- i-independent w staging bases: ws[buf][o*145+off] <- wgt[(o*32+i)*8649 + p*279 + q0*9 + off]
    int bw[10];
    const int lim = (qg == 0) ? 143 : 134;   // valid words per o-seg - 1 (16 vs 15 q's)
    const int pqb = p * 279 + q0 * 9;
#pragma unroll
    for (int j = 0; j < 10; ++j) {
        int f = t + j * 512; f = (f < 4639) ? f : 4639;
        const int os  = f / 145;
        const int off = f - os * 145;
        const int go  = (off < lim) ? off : lim;          // pad words dup-load, never read
        bw[j] = os * (32 * 8649) + pqb + go;
    }

#pragma unroll
    for (int j = 0; j < 10; ++j)
        GLD_LDS(wgt + (size_t)(bw[j] + i0 * 8649), &ws[0][j * 512 + waveBase]);

    float acc[8];
#pragma unroll
    for (int b = 0; b < 8; ++b) acc[b] = 0.f;

    __syncthreads();                  // x + w[i0] staged (barrier drains vmcnt)

#pragma unroll
    for (int ii = 0; ii < 4; ++ii) {
        if (ii < 3) {                 // prefetch next i into other buffer
            const int inext = i0 + ii + 1;
#pragma unroll
            for (int j = 0; j < 10; ++j)
                GLD_LDS(wgt + (size_t)(bw[j] + inext * 8649), &ws[(ii + 1) & 1][j * 512 + waveBase]);
        }

        const float* wb = ws[ii & 1];
        float wv[9];
        const int wbase = o * 145 + dq * 9;               // stride-145 across o-lanes: bank-bijective
#pragma unroll
        for (int k = 0; k < 9; ++k) wv[k] = wb[wbase + k];

        const int xdq = 2 * dq;
#pragma unroll
        for (int kh = 0; kh < 3; ++kh) {
#pragma unroll
            for (int b = 0; b < 8; ++b) {
                const int base = ((b * 4 + ii) * 3 + kh) * 36 + xdq;   // one base reg + imm offsets
                const float2 a = *reinterpret_cast<const float2*>(&xs[base]);  // cols 2q,2q+1
                const float c1 = xs[base + 2];                                  // col 2q+2
                acc[b] += wv[kh * 3 + 0] * a.x + wv[kh * 3 + 1] * a.y + wv[kh * 3 + 2] * c1;
            }
        }
        __syncthreads();              // compute(ii) reads done before ws[ii&1] is re-staged
    }

    if (q <= 30) {
        if (USE_WS) {
            // part[((ig*8+b)*961 + p*31+q)*32 + o] : lane addr = base + b*30752 + t  -> coalesced
            const int pq = p * 31 + q;
#pragma unroll
            for (int b = 0; b < 8; ++b)
                outOrPart[((size_t)(ig * 8 + b) * 961 + pq) * 32 + o] = acc[b];
        } else {
#pragma unroll
            for (int b = 0; b < 8; ++b)
                atomicAdd(&outOrPart[(((size_t)b * 32 + o) * 31 + p) * 31 + q], acc[b]);
        }
    }
}

__global__ __launch_bounds__(256) void lc2d_reduce(const float* __restrict__ part,
                                                   float* __restrict__ out) {
    const int u = blockIdx.x * 256 + threadIdx.x;   // grid exactly covers 246016
    float s = 0.f;
#pragma unroll
    for (int ig = 0; ig < 8; ++ig) s += part[(size_t)ig * NPART + u];   // 8 coalesced streams
    const int o = u & 31;
    const int r = u >> 5;
    const int b = r / 961;
    const int pq = r - b * 961;
    out[(size_t)(b * 32 + o) * 961 + pq] = s;
}

extern "C" void kernel_launch(void* const* d_in, const int* in_sizes, int n_in,
                              void* d_out, int out_size, void* d_ws, size_t ws_size,
                              hipStream_t stream) {
    const float* x = (const float*)d_in[0];
    const float* w = (const float*)d_in[1];
    float* out = (float*)d_out;

    if (ws_size >= WS_NEED) {
        float* part = (float*)d_ws;
        lc2d_kernel<true><<<dim3(31 * 2 * 8), dim3(512), 0, stream>>>(x, w, part);
        lc2d_reduce<<<dim3(NPART / 256), dim3(256), 0, stream>>>(part, out);
    } else {
        hipMemsetAsync(out, 0, (size_t)out_size * sizeof(float), stream);
        lc2d_kernel<false><<<dim3(31 * 2 * 8), dim3(512), 0, stream>>>(x, w, out);
    }
}

// Round 8
// 86.074 us; speedup vs baseline: 2.0239x; 1.4942x over previous
//
#include <hip/hip_runtime.h>

// LocallyConnected2d: out[b,o,p,q] = sum_{i,kh,kw} x[b,i,2p+kh,2q+kw] * w[o,i,p,q,kh*3+kw]
// x: (8,32,64,64) f32, w: (1,32,32,31,31,9) f32, out: (8,32,31,31) f32
//
// Lanes = o (32) so x reads are wave-broadcast; block = (p, qg of 16 q, ig of 4 i),
// 512 thr = 32 o x 16 dq. 496 blocks; each stages its EXCLUSIVE weight slice
// (weight read once device-wide) + a 14 KB x slice via global_load_lds.
//  - x LDS: [b][ii][kh][36] - reads broadcast across o-lanes.
//  - w LDS: [o][145] (odd stride -> o-lane reads bank-bijective), dbuf per i.
//  - partials -> d_ws (coalesced, addr = base + t) + tiny reduce kernel.
// R7 spilled: full ii-unroll software-pipelined 4 iterations -> >128 VGPR live
// at the (512,2) cap -> 78 MB of scratch writebacks (WRITE_SIZE) at FETCH +7MB
// (spill re-reads L2-hit). Fix: #pragma unroll 1 on ii, recompute staging
// offsets (drop bw[10]), base+imm-offset LDS reads. Live set ~40 VGPR.

#define NPART 246016              // 8b * 961pq * 32o floats per ig-copy
#define WS_NEED ((size_t)8 * NPART * 4)

#define GLD_LDS(gp, lp)                                              \
    __builtin_amdgcn_global_load_lds(                                \
        (const __attribute__((address_space(1))) void*)(gp),         \
        (__attribute__((address_space(3))) void*)(lp), 4, 0, 0)

template <bool USE_WS>
__global__ __launch_bounds__(512, 2) void lc2d_kernel(const float* __restrict__ x,
                                                      const float* __restrict__ wgt,
                                                      float* __restrict__ outOrPart) {
    __shared__ float xs[3584];        // 3456 used + stage-pad (7*512)
    __shared__ float wsb[2][5120];    // 4640 used + stage-pad (10*512), dbuf

    const int t  = threadIdx.x;
    const int o  = t & 31;
    const int dq = t >> 5;            // 0..15
    const int bid = blockIdx.x;
    const int p  = bid >> 4;          // 0..30
    const int qg = (bid >> 3) & 1;
    const int ig = bid & 7;
    const int i0 = ig * 4;
    const int q0 = qg << 4;
    const int q  = q0 + dq;           // q=31 (qg=1,dq=15) computes dup, never stored
    const int waveBase = t & ~63;

    // ---- stage x: xs[((b*4+ii)*3+kh)*36 + c] = x[b][i0+ii][2p+kh][2*q0+min(c,xlim)]
    const int xlim = 62 - 2 * q0;     // keep cols in-bounds (62 qg0 / 30 qg1)
    const int xrow = 2 * p;
#pragma unroll
    for (int j = 0; j < 7; ++j) {
        int f = t + j * 512; f = (f < 3455) ? f : 3455;   // clamp GLOBAL addr only; LDS dest stays linear
        const int r  = f / 36;
        const int c  = f - r * 36;
        const int b  = r / 12;
        const int r2 = r - b * 12;
        const int ii = r2 / 3;
        const int kh = r2 - ii * 3;
        const int gc = (c < xlim) ? c : xlim;
        const float* gp = x + ((size_t)b * 131072 + (size_t)(i0 + ii) * 4096
                               + (size_t)(xrow + kh) * 64 + 2 * q0 + gc);
        GLD_LDS(gp, &xs[j * 512 + waveBase]);
    }

    // ---- stage w for i0 into buf0: wsb[0][os*145+off] <- wgt[os*276768 + pqb + off + i*8649]
    const int lim = (qg == 0) ? 143 : 134;   // last valid word per o-seg (pad words dup, never read)
    const int pqb = p * 279 + q0 * 9;
#pragma unroll
    for (int j = 0; j < 10; ++j) {
        int f = t + j * 512; f = (f < 4639) ? f : 4639;
        const int os  = f / 145;
        const int off = f - os * 145;
        const int go  = (off < lim) ? off : lim;
        GLD_LDS(wgt + (size_t)(os * 276768 + pqb + go + i0 * 8649),
                &wsb[0][j * 512 + waveBase]);
    }

    float acc[8];
#pragma unroll
    for (int b = 0; b < 8; ++b) acc[b] = 0.f;

    __syncthreads();                  // x + w[i0] staged (barrier drains vmcnt)

    const int wvbase = o * 145 + dq * 9;   // stride-145 across o-lanes: bank-bijective
    const int xdq = 2 * dq;

#pragma unroll 1                      // NO cross-ii pipelining -> bounded live set
    for (int ii = 0; ii < 4; ++ii) {
        const float* wb = wsb[ii & 1];
        float* wn = wsb[(ii + 1) & 1];

        if (ii < 3) {                 // prefetch next i into other buffer (offsets recomputed)
            const int iw = (i0 + ii + 1) * 8649;
#pragma unroll
            for (int j = 0; j < 10; ++j) {
                int f = t + j * 512; f = (f < 4639) ? f : 4639;
                const int os  = f / 145;
                const int off = f - os * 145;
                const int go  = (off < lim) ? off : lim;
                GLD_LDS(wgt + (size_t)(os * 276768 + pqb + go + iw),
                        &wn[j * 512 + waveBase]);
            }
        }

        float wv[9];
#pragma unroll
        for (int k = 0; k < 9; ++k) wv[k] = wb[wvbase + k];

        const int xb0 = ii * 108 + xdq;                   // one base reg; rest imm offsets
#pragma unroll
        for (int kh = 0; kh < 3; ++kh) {
#pragma unroll
            for (int b = 0; b < 8; ++b) {
                const int base = xb0 + (b * 12 + kh) * 36;
                const float2 a = *reinterpret_cast<const float2*>(&xs[base]);  // cols 2q,2q+1
                const float c1 = xs[base + 2];                                  // col 2q+2
                acc[b] += wv[kh * 3 + 0] * a.x + wv[kh * 3 + 1] * a.y + wv[kh * 3 + 2] * c1;
            }
        }
        __syncthreads();              // wb reads done before re-stage; wn staging visible
    }

    if (q <= 30) {
        if (USE_WS) {
            // part[((ig*8+b)*961 + p*31+q)*32 + o] : lane addr = base + b*30752 + t -> coalesced
            const int pq = p * 31 + q;
#pragma unroll
            for (int b = 0; b < 8; ++b)
                outOrPart[((size_t)(ig * 8 + b) * 961 + pq) * 32 + o] = acc[b];
        } else {
#pragma unroll
            for (int b = 0; b < 8; ++b)
                atomicAdd(&outOrPart[(((size_t)b * 32 + o) * 31 + p) * 31 + q], acc[b]);
        }
    }
}

__global__ __launch_bounds__(256) void lc2d_reduce(const float* __restrict__ part,
                                                   float* __restrict__ out) {
    const int u = blockIdx.x * 256 + threadIdx.x;   // grid exactly covers 246016
    float s = 0.f;
#pragma unroll
    for (int ig = 0; ig < 8; ++ig) s += part[(size_t)ig * NPART + u];   // 8 coalesced streams
    const int o = u & 31;
    const int r = u >> 5;
    const int b = r / 961;
    const int pq = r - b * 961;
    out[(size_t)(b * 32 + o) * 961 + pq] = s;
}

extern "C" void kernel_launch(void* const* d_in, const int* in_sizes, int n_in,
                              void* d_out, int out_size, void* d_ws, size_t ws_size,
                              hipStream_t stream) {
    const float* x = (const float*)d_in[0];
    const float* w = (const float*)d_in[1];
    float* out = (float*)d_out;

    if (ws_size >= WS_NEED) {
        float* part = (float*)d_ws;
        lc2d_kernel<true><<<dim3(31 * 2 * 8), dim3(512), 0, stream>>>(x, w, part);
        lc2d_reduce<<<dim3(NPART / 256), dim3(256), 0, stream>>>(part, out);
    } else {
        hipMemsetAsync(out, 0, (size_t)out_size * sizeof(float), stream);
        lc2d_kernel<false><<<dim3(31 * 2 * 8), dim3(512), 0, stream>>>(x, w, out);
    }
}

// Round 10
// 85.028 us; speedup vs baseline: 2.0488x; 1.0123x over previous
//
#include <hip/hip_runtime.h>

// LocallyConnected2d: out[b,o,p,q] = sum_{i,kh,kw} x[b,i,2p+kh,2q+kw] * w[o,i,p,q,kh*3+kw]
// x: (8,32,64,64) f32, w: (1,32,32,31,31,9) f32, out: (8,32,31,31) f32
//
// Block = (p, qg, ig): 16 q x 4 i x all 32 o. 512 thr = 16 ol x 2 bh x 16 dq;
// thread computes 2 o (ol, ol+16) x 4 b (bh*4..+3) -> FMA:ds_read 72:42 per ii.
// Weight read once device-wide via global_load_lds dword stream into [o][145]
// LDS (odd stride: o-lane reads bank-bijective). x staged as FULL 64-word rows
// with 16B global_load_lds (3 issues/thread); x reads broadcast across ol.
// Partials -> d_ws coalesced + reduce kernel (atomics were 106MB RMW, R6).
// unroll 1 on ii: full-unroll software-pipelining spills at the 128 cap (R7).
// R9 BUG FIXED: x read base was missing +2*q0 after the move to full-row
// staging -> qg=1 blocks read cols 0..31 instead of 32..62 (absmax 107).

#define NPART 246016              // 8b * 961pq * 32o floats per ig-copy
#define WS_NEED ((size_t)8 * NPART * 4)

#define GLD4(gp, lp)                                                 \
    __builtin_amdgcn_global_load_lds(                                \
        (const __attribute__((address_space(1))) void*)(gp),         \
        (__attribute__((address_space(3))) void*)(lp), 4, 0, 0)
#define GLD16(gp, lp)                                                \
    __builtin_amdgcn_global_load_lds(                                \
        (const __attribute__((address_space(1))) void*)(gp),         \
        (__attribute__((address_space(3))) void*)(lp), 16, 0, 0)

template <bool USE_WS>
__global__ __launch_bounds__(512, 2) void lc2d_kernel(const float* __restrict__ x,
                                                      const float* __restrict__ wgt,
                                                      float* __restrict__ outOrPart) {
    __shared__ float xs[6144];        // [b8][ii4][kh3][64 words] = 24 KB
    __shared__ float wsb[2][5120];    // [o32][145] = 4640 used + pad, dbuf = 40 KB

    const int t  = threadIdx.x;
    const int ol = t & 15;            // o-lane: handles o=ol and o=ol+16
    const int bh = (t >> 4) & 1;      // b-half: b in [bh*4, bh*4+4)
    const int dq = t >> 5;            // 0..15
    const int bid = blockIdx.x;
    const int p  = bid >> 4;          // 0..30
    const int qg = (bid >> 3) & 1;
    const int ig = bid & 7;
    const int i0 = ig * 4;
    const int q0 = qg << 4;
    const int q  = q0 + dq;           // q=31 computes dup (clamped w), never stored
    const int waveBase = t & ~63;

    // ---- stage x: full rows, 16B chunks. chunk g -> row r=g/16, words (g%16)*4..+3
    //      row r = (b*4+ii)*3 + kh ; global row base is 64-word (256B) aligned.
#pragma unroll
    for (int j = 0; j < 3; ++j) {
        const int g  = j * 512 + t;   // 0..1535, exact (no clamp)
        const int r  = g >> 4;
        const int cw = (g & 15) << 2;
        const int b  = r / 12;
        const int r2 = r - b * 12;
        const int ii = r2 / 3;
        const int kh = r2 - ii * 3;
        const float* gp = x + (size_t)b * 131072 + (size_t)(i0 + ii) * 4096
                            + (size_t)(2 * p + kh) * 64 + cw;
        GLD16(gp, &xs[4 * (j * 512 + waveBase)]);
    }

    // ---- w staging: wsb[buf][os*145+off] <- wgt[os*276768 + pqb + min(off,lim) + i*8649]
    const int lim = (qg == 0) ? 143 : 134;   // last valid word per o-seg (pads dup, never read)
    const int pqb = p * 279 + q0 * 9;
#define STAGE_W(i, buf)                                                          \
    {                                                                            \
        _Pragma("unroll")                                                        \
        for (int j = 0; j < 10; ++j) {                                           \
            int f = t + j * 512; f = (f < 4639) ? f : 4639;                      \
            const int os  = f / 145;                                             \
            const int off = f - os * 145;                                        \
            const int go  = (off < lim) ? off : lim;                             \
            GLD4(wgt + (size_t)os * 276768 + pqb + go + (size_t)(i) * 8649,      \
                 &wsb[buf][j * 512 + waveBase]);                                 \
        }                                                                        \
    }

    STAGE_W(i0, 0);

    float acc[2][4];
#pragma unroll
    for (int lo = 0; lo < 2; ++lo)
#pragma unroll
        for (int bi = 0; bi < 4; ++bi) acc[lo][bi] = 0.f;

    __syncthreads();                  // x + w[i0] staged (barrier drains vmcnt)

    const int wv0 = ol * 145 + dq * 9;
    const int wv1 = (ol + 16) * 145 + dq * 9;

#pragma unroll 1                      // no cross-ii pipelining -> bounded live set
    for (int ii = 0; ii < 4; ++ii) {
        const float* wb = wsb[ii & 1];

        if (ii < 3) STAGE_W(i0 + ii + 1, (ii + 1) & 1);   // prefetch, drained at end barrier

        float wv[2][9];
#pragma unroll
        for (int k = 0; k < 9; ++k) {
            wv[0][k] = wb[wv0 + k];
            wv[1][k] = wb[wv1 + k];
        }

        const int xb = bh * 3072 + ii * 192 + 2 * q0 + 2 * dq;  // col = 2*(q0+dq)  [R9 fix]
#pragma unroll
        for (int kh = 0; kh < 3; ++kh) {
#pragma unroll
            for (int bi = 0; bi < 4; ++bi) {
                const int base = xb + bi * 768 + kh * 64;
                const float2 a = *reinterpret_cast<const float2*>(&xs[base]);  // cols 2q,2q+1
                const float c1 = xs[base + 2];                                  // col 2q+2
#pragma unroll
                for (int lo = 0; lo < 2; ++lo)
                    acc[lo][bi] += wv[lo][kh * 3 + 0] * a.x
                                 + wv[lo][kh * 3 + 1] * a.y
                                 + wv[lo][kh * 3 + 2] * c1;
            }
        }
        __syncthreads();              // wb reads done before re-stage; prefetch visible
    }

    if (q <= 30) {
        const int pq = p * 31 + q;
        if (USE_WS) {
            // part[((ig*8+b)*961 + pq)*32 + o] : per (bi,lo) store, lanes form
            // contiguous 16-word runs (ol fast) -> coalesced
#pragma unroll
            for (int lo = 0; lo < 2; ++lo)
#pragma unroll
                for (int bi = 0; bi < 4; ++bi)
                    outOrPart[((size_t)(ig * 8 + bh * 4 + bi) * 961 + pq) * 32 + ol + lo * 16]
                        = acc[lo][bi];
        } else {
#pragma unroll
            for (int lo = 0; lo < 2; ++lo)
#pragma unroll
                for (int bi = 0; bi < 4; ++bi)
                    atomicAdd(&outOrPart[(((size_t)(bh * 4 + bi) * 32 + ol + lo * 16) * 31 + p) * 31 + q],
                              acc[lo][bi]);
        }
    }
}

__global__ __launch_bounds__(256) void lc2d_reduce(const float* __restrict__ part,
                                                   float* __restrict__ out) {
    const int u = blockIdx.x * 256 + threadIdx.x;   // grid exactly covers 246016
    float s = 0.f;
#pragma unroll
    for (int ig = 0; ig < 8; ++ig) s += part[(size_t)ig * NPART + u];   // 8 coalesced streams
    const int o = u & 31;
    const int r = u >> 5;
    const int b = r / 961;
    const int pq = r - b * 961;
    out[(size_t)(b * 32 + o) * 961 + pq] = s;
}

extern "C" void kernel_launch(void* const* d_in, const int* in_sizes, int n_in,
                              void* d_out, int out_size, void* d_ws, size_t ws_size,
                              hipStream_t stream) {
    const float* x = (const float*)d_in[0];
    const float* w = (const float*)d_in[1];
    float* out = (float*)d_out;

    if (ws_size >= WS_NEED) {
        float* part = (float*)d_ws;
        lc2d_kernel<true><<<dim3(31 * 2 * 8), dim3(512), 0, stream>>>(x, w, part);
        lc2d_reduce<<<dim3(NPART / 256), dim3(256), 0, stream>>>(part, out);
    } else {
        hipMemsetAsync(out, 0, (size_t)out_size * sizeof(float), stream);
        lc2d_kernel<false><<<dim3(31 * 2 * 8), dim3(512), 0, stream>>>(x, w, out);
    }
}